// Round 3
// baseline (131.300 us; speedup 1.0000x reference)
//
#include <hip/hip_runtime.h>
#include <math.h>

#define LAYERS  8
#define FEAT    3072
#define NCLASS  10
#define DIM     4096
#define ST      68            // padded LDS row stride (floats); ST%4==0 -> b128-able, ST%32==4
#define SBF     (ST * 64)     // per-stream LDS float offset (4352 floats = 17408 B)

typedef float v2f __attribute__((ext_vector_type(2)));
typedef float v4f __attribute__((ext_vector_type(4)));

// prefix-xor (inverse Gray) of 6-bit value; compile-time under unroll
__device__ __forceinline__ int px6c(int r) {
    int u = r ^ (r >> 1); u ^= u >> 2; u ^= u >> 4; return u & 63;
}
__device__ __forceinline__ int gray6(int r) { return (r ^ (r >> 1)) & 63; }

__device__ __forceinline__ float getc(const v2f v[32], int u) {
    return (u & 1) ? v[u >> 1].y : v[u >> 1].x;
}
__device__ __forceinline__ void setc(v2f v[32], int u, float x) {
    if (u & 1) v[u >> 1].y = x; else v[u >> 1].x = x;
}
__device__ __forceinline__ float bpermf(int addr, float x) {
    return __int_as_float(__builtin_amdgcn_ds_bpermute(addr, __float_as_int(x)));
}

// ---- packed fp32 math (VOP3P). v2f = 64-bit VGPR pair. Compiler won't form
//      v_pk_* from <2 x float> IR on its own (R2 evidence: ~29k scalar VALU) ----
__device__ __forceinline__ v2f pk_mul(v2f a, v2f b) {
    v2f d; asm("v_pk_mul_f32 %0, %1, %2" : "=v"(d) : "v"(a), "v"(b)); return d;
}
__device__ __forceinline__ v2f pk_fma(v2f a, v2f b, v2f c) {
    v2f d; asm("v_pk_fma_f32 %0, %1, %2, %3" : "=v"(d) : "v"(a), "v"(b), "v"(c)); return d;
}
// src0 swapped (lo<->hi) via op_sel: lo result reads a.hi, hi result reads a.lo
__device__ __forceinline__ v2f pk_fma_swap(v2f a, v2f b, v2f c) {
    v2f d; asm("v_pk_fma_f32 %0, %1, %2, %3 op_sel:[1,0,0] op_sel_hi:[0,1,1]"
               : "=v"(d) : "v"(a), "v"(b), "v"(c));
    return d;
}

// ---- butterfly stages (packed). Same math as R2's butterflies6 / _renamed ----
// plain stage 0: v[i] = a*c2 + swap(a)*ms,  ms = {-s, s}
__device__ __forceinline__ void bf_s0(v2f v[32], float c, float s) {
    const v2f c2 = {c, c}, ms = {-s, s};
#pragma unroll
    for (int i = 0; i < 32; ++i) {
        v2f a = v[i];
        v[i] = pk_fma_swap(a, ms, pk_mul(a, c2));
    }
}
// plain stage p>=1: pairs (i0, i0|(1<<(p-1)))
__device__ __forceinline__ void bf_sp(v2f v[32], int p, float c, float s) {
    const v2f c2 = {c, c}, s2 = {s, s}, ns2 = {-s, -s};
#pragma unroll
    for (int i0 = 0; i0 < 32; ++i0) {
        if (i0 & (1 << (p - 1))) continue;
        const int i1 = i0 | (1 << (p - 1));
        v2f a = v[i0], e = v[i1];
        v[i0] = pk_fma(e, ns2, pk_mul(a, c2));
        v[i1] = pk_fma(a, s2,  pk_mul(e, c2));
    }
}
// renamed stage 0 (deferred-GrayA conjugation)
__device__ __forceinline__ void bfr_s0(v2f v[32], float c, float s) {
    const v2f c2 = {c, c}, msA = {-s, s}, msB = {s, -s};
#pragma unroll
    for (int k = 0; k < 32; ++k) {
        v2f a = v[k];
        v[k] = pk_fma_swap(a, (k & 1) ? msB : msA, pk_mul(a, c2));
    }
}
// renamed stage b=1..4: pairs (m, m^((1<<b)-1)), swapped partner, sign by m&(1<<b)
__device__ __forceinline__ void bfr_sb(v2f v[32], int b, float c, float s) {
    const v2f c2 = {c, c};
#pragma unroll
    for (int m = 0; m < 32; ++m) {
        if (m & (1 << (b - 1))) continue;
        const int part = m ^ ((1 << b) - 1);
        const float sg = (m & (1 << b)) ? -s : s;
        const v2f sg2 = {sg, sg}, nsg2 = {-sg, -sg};
        v2f A = v[m], E = v[part];
        v[m]    = pk_fma_swap(E, nsg2, pk_mul(A, c2));   // A*c2 - swap(E)*sg2
        v[part] = pk_fma_swap(A, sg2,  pk_mul(E, c2));   // swap(A)*sg2 + E*c2
    }
}
// renamed stage b=5: pairs (m, m^31), snl = psgn*s
__device__ __forceinline__ void bfr_s5(v2f v[32], float c, float snl) {
    const v2f c2 = {c, c}, sg2 = {snl, snl}, nsg2 = {-snl, -snl};
#pragma unroll
    for (int m = 0; m < 16; ++m) {
        const int part = m ^ 31;
        v2f A = v[m], E = v[part];
        v[m]    = pk_fma_swap(E, nsg2, pk_mul(A, c2));
        v[part] = pk_fma_swap(A, sg2,  pk_mul(E, c2));
    }
}
__device__ __forceinline__ void bf6_full(v2f v[32], const float* __restrict__ cl,
                                         const float* __restrict__ sl, int off) {
    bf_s0(v, cl[off], sl[off]);
#pragma unroll
    for (int p = 1; p < 6; ++p) bf_sp(v, p, cl[off - p], sl[off - p]);
}

// One wave per block; two batch states per wave (ILP, zero barriers, in-order DS).
// DS chunks (<=14 ops) hand-interleaved between the OTHER stream's butterfly
// stages so the 15-deep lgkm queue never blocks issue. LDS: two 17.4KB regions.
__global__ __launch_bounds__(64, 1)
void qnn_kernel(const float* __restrict__ x,
                const float* __restrict__ ang,
                const float* __restrict__ W,
                const float* __restrict__ bias,
                float* __restrict__ out,
                int batch)
{
    __shared__ __attribute__((aligned(16))) float lds[2 * SBF];   // 34816 B
    __shared__ float cst[96], snt[96];

    const int t = threadIdx.x;          // 0..63, single wave per block
    const int b = blockIdx.x;
    const int b0 = 2 * b, b1 = 2 * b + 1;
    const bool has1 = (b1 < batch);

    // ---- trig tables (96 angles); single wave, in-order DS -> no barrier ----
    {
        float a0 = ang[t];
        cst[t] = cosf(a0);
        snt[t] = sinf(a0);
        if (t < 32) {
            float a1 = ang[64 + t];
            cst[64 + t] = cosf(a1);
            snt[64 + t] = sinf(a1);
        }
    }

    // ---- load psi0 for both streams in B layout: v[r] = psi[64r + t] ----
    v2f v0[32], v1[32];
    {
        const float* xb = x + (size_t)b0 * FEAT;
#pragma unroll
        for (int r = 0; r < 64; ++r) {
            if (r < FEAT / 64) setc(v0, r, xb[64 * r + t]);
            else               setc(v0, r, 0.f);
        }
    }
    if (has1) {
        const float* xb = x + (size_t)b1 * FEAT;
#pragma unroll
        for (int r = 0; r < 64; ++r) {
            if (r < FEAT / 64) setc(v1, r, xb[64 * r + t]);
            else               setc(v1, r, 0.f);
        }
    } else {
#pragma unroll
        for (int i = 0; i < 32; ++i) v1[i] = (v2f){0.f, 0.f};
    }

    // ---- ||x||^2 per stream (normalization deferred: circuit is linear) ----
    float invn0, invn1;
    {
        v2f s2 = {0.f, 0.f};
#pragma unroll
        for (int i = 0; i < 32; ++i) s2 = pk_fma(v0[i], v0[i], s2);
        float ss = s2.x + s2.y;
#pragma unroll
        for (int o = 1; o < 64; o <<= 1) ss += __shfl_xor(ss, o, 64);
        invn0 = 1.0f / ss;
    }
    {
        v2f s2 = {0.f, 0.f};
#pragma unroll
        for (int i = 0; i < 32; ++i) s2 = pk_fma(v1[i], v1[i], s2);
        float ss = s2.x + s2.y;
#pragma unroll
        for (int o = 1; o < 64; o <<= 1) ss += __shfl_xor(ss, o, 64);
        invn1 = 1.0f / ss;           // inf when stream 1 absent; never stored
    }

    // ---- anti-lock-step skew keyed on SIMD id (1 wave/SIMD) ----
    {
        const int slot = __builtin_amdgcn_s_getreg(4 | (4 << 6) | (1 << 11)) & 3;  // HW_ID.SIMD_ID
#pragma unroll 1
        for (int i = 0; i < slot; ++i) __builtin_amdgcn_s_sleep(12);   // 12*64 cyc
    }

    // ---- per-lane constants ----
    int px = t ^ (t >> 1); px ^= px >> 2; px ^= px >> 4; px &= 63;  // px6(t)
    const int A0 = 4 * px;                    // bpermute byte addrs (GrayB)
    const int A1 = 4 * (px ^ 63);
    const int u0 = t & 1;
    const float psgn = u0 ? -1.f : 1.f;       // parity sign for renamed b=5
    const int gtl = gray6(t);
    const int bp  = gtl + 32 * ST * u0;       // folded-GrayA store bases
    const int bm  = gtl - 32 * ST * u0;

    // ---- chunked DS helpers (bounds are literals at call sites -> unrolled) ----
    auto stR = [&](const v2f* vv, const int SB, int i0, int i1) {   // b128 row stores
#pragma unroll
        for (int i = i0; i < i1; ++i) {
            v4f q = {vv[2 * i].x, vv[2 * i].y, vv[2 * i + 1].x, vv[2 * i + 1].y};
            *(v4f*)(lds + SB + ST * t + 4 * i) = q;
        }
    };
    auto rdC = [&](v2f* vv, const int SB, int u0c, int u1c) {       // b32 col reads
#pragma unroll
        for (int u = u0c; u < u1c; ++u) setc(vv, u, lds[SB + t + ST * u]);
    };
    auto fS = [&](const v2f* vv, const int SB, int s0, int s1) {    // folded-GrayA stores
#pragma unroll
        for (int s = s0; s < s1; ++s) {
            const int g = gray6(s);                                 // compile-time
            lds[SB + ((g & 32) ? bm : bp) + ST * g] = getc(vv, s);
        }
    };
    auto rR = [&](v2f* vv, const int SB, int i0, int i1) {          // b128 row reads
#pragma unroll
        for (int i = i0; i < i1; ++i) {
            v4f q = *(const v4f*)(lds + SB + ST * t + 4 * i);
            vv[2 * i]     = (v2f){q.x, q.y};
            vv[2 * i + 1] = (v2f){q.z, q.w};
        }
    };
    auto gG = [&](const v2f* vv, float* n, int r0, int r1) {        // GrayB gather
#pragma unroll
        for (int r = r0; r < r1; ++r) {
            const int sr = px6c(r);                                 // compile-time
            n[r] = bpermf((sr & 1) ? A1 : A0, getc(vv, sr));
        }
    };
    auto gA = [&](v2f* vv, const float* n) {                        // GrayB apply
#pragma unroll
        for (int r = 0; r < 64; ++r) setc(vv, r, n[r]);
    };

    // ---- layer 0 (even, clean): B-phase, transpose B->A, A-phase ----
    {
        const float* cl = cst;
        const float* sl = snt;
        bf6_full(v0, cl, sl, 5);                     // cold start, unhidden
        stR(v0, 0, 0, 16);     bf_s0(v1, cl[5], sl[5]);
        rdC(v0, 0, 0, 13);     bf_sp(v1, 1, cl[4], sl[4]);
        rdC(v0, 0, 13, 26);    bf_sp(v1, 2, cl[3], sl[3]);
        rdC(v0, 0, 26, 39);    bf_sp(v1, 3, cl[2], sl[2]);
        rdC(v0, 0, 39, 52);    bf_sp(v1, 4, cl[1], sl[1]);
        rdC(v0, 0, 52, 64);    bf_sp(v1, 5, cl[0], sl[0]);
        stR(v1, SBF, 0, 16);   bf_s0(v0, cl[11], sl[11]);
        rdC(v1, SBF, 0, 13);   bf_sp(v0, 1, cl[10], sl[10]);
        rdC(v1, SBF, 13, 26);  bf_sp(v0, 2, cl[9],  sl[9]);
        rdC(v1, SBF, 26, 39);  bf_sp(v0, 3, cl[8],  sl[8]);
        rdC(v1, SBF, 39, 52);  bf_sp(v0, 4, cl[7],  sl[7]);
        rdC(v1, SBF, 52, 64);  bf_sp(v0, 5, cl[6],  sl[6]);
        bf6_full(v1, cl, sl, 11);                    // rd1 tail drains underneath
        // GrayA(0): deferred into layer 1
    }

#pragma unroll 1
    for (int p = 0; p < 4; ++p) {
        float n0[64], n1[64];
        const float* cl = cst + (2 * p + 1) * 12;
        const float* sl = snt + (2 * p + 1) * 12;
        const float snl = psgn * sl[6];

        // ======== odd layer 2p+1: renamed A-phase, folded transpose, B-phase ========
        // ren0 full (pure VALU; previous layer's DS is long drained)
        bfr_s0(v0, cl[11], sl[11]);
        bfr_sb(v0, 1, cl[10], sl[10]);
        bfr_sb(v0, 2, cl[9],  sl[9]);
        bfr_sb(v0, 3, cl[8],  sl[8]);
        bfr_sb(v0, 4, cl[7],  sl[7]);
        bfr_s5(v0, cl[6], snl);
        // fs0 + rr0 interleaved with ren1 stages
        fS(v0, 0, 0, 14);      bfr_s0(v1, cl[11], sl[11]);
        fS(v0, 0, 14, 28);     bfr_sb(v1, 1, cl[10], sl[10]);
        fS(v0, 0, 28, 42);     bfr_sb(v1, 2, cl[9],  sl[9]);
        fS(v0, 0, 42, 56);     bfr_sb(v1, 3, cl[8],  sl[8]);
        fS(v0, 0, 56, 64);
        rR(v0, 0, 0, 3);       bfr_sb(v1, 4, cl[7],  sl[7]);
        rR(v0, 0, 3, 10);      bfr_s5(v1, cl[6], snl);
        rR(v0, 0, 10, 16);
        // fs1 + rr1 interleaved with bf0b(5) stages
        fS(v1, SBF, 0, 14);    bf_s0(v0, cl[5], sl[5]);
        fS(v1, SBF, 14, 28);   bf_sp(v0, 1, cl[4], sl[4]);
        fS(v1, SBF, 28, 42);   bf_sp(v0, 2, cl[3], sl[3]);
        fS(v1, SBF, 42, 56);   bf_sp(v0, 3, cl[2], sl[2]);
        fS(v1, SBF, 56, 64);
        rR(v1, SBF, 0, 3);     bf_sp(v0, 4, cl[1], sl[1]);
        rR(v1, SBF, 3, 10);    bf_sp(v0, 5, cl[0], sl[0]);
        rR(v1, SBF, 10, 16);

        if (p < 3) {
            // gray0 gather interleaved with bf1b(5) stages
            gG(v0, n0, 0, 11);     bf_s0(v1, cl[5], sl[5]);
            gG(v0, n0, 11, 22);    bf_sp(v1, 1, cl[4], sl[4]);
            gG(v0, n0, 22, 33);    bf_sp(v1, 2, cl[3], sl[3]);
            gG(v0, n0, 33, 44);    bf_sp(v1, 3, cl[2], sl[2]);
            gG(v0, n0, 44, 55);    bf_sp(v1, 4, cl[1], sl[1]);
            gG(v0, n0, 55, 64);    bf_sp(v1, 5, cl[0], sl[0]);
            gA(v0, n0);

            // ======== even layer 2p+2 (clean) ========
            const float* cle = cst + (2 * p + 2) * 12;
            const float* sle = snt + (2 * p + 2) * 12;
            // gray1 gather interleaved with bf0a(5) stages
            gG(v1, n1, 0, 11);     bf_s0(v0, cle[5], sle[5]);
            gG(v1, n1, 11, 22);    bf_sp(v0, 1, cle[4], sle[4]);
            gG(v1, n1, 22, 33);    bf_sp(v0, 2, cle[3], sle[3]);
            gG(v1, n1, 33, 44);    bf_sp(v0, 3, cle[2], sle[2]);
            gG(v1, n1, 44, 55);    bf_sp(v0, 4, cle[1], sle[1]);
            gG(v1, n1, 55, 64);    bf_sp(v0, 5, cle[0], sle[0]);
            gA(v1, n1);
            // st0 + rd0 interleaved with bf1a(5) stages
            stR(v0, 0, 0, 16);     bf_s0(v1, cle[5], sle[5]);
            rdC(v0, 0, 0, 13);     bf_sp(v1, 1, cle[4], sle[4]);
            rdC(v0, 0, 13, 26);    bf_sp(v1, 2, cle[3], sle[3]);
            rdC(v0, 0, 26, 39);    bf_sp(v1, 3, cle[2], sle[2]);
            rdC(v0, 0, 39, 52);    bf_sp(v1, 4, cle[1], sle[1]);
            rdC(v0, 0, 52, 64);    bf_sp(v1, 5, cle[0], sle[0]);
            // st1 + rd1 interleaved with bf0b(11) stages
            stR(v1, SBF, 0, 16);   bf_s0(v0, cle[11], sle[11]);
            rdC(v1, SBF, 0, 13);   bf_sp(v0, 1, cle[10], sle[10]);
            rdC(v1, SBF, 13, 26);  bf_sp(v0, 2, cle[9],  sle[9]);
            rdC(v1, SBF, 26, 39);  bf_sp(v0, 3, cle[8],  sle[8]);
            rdC(v1, SBF, 39, 52);  bf_sp(v0, 4, cle[7],  sle[7]);
            rdC(v1, SBF, 52, 64);  bf_sp(v0, 5, cle[6],  sle[6]);
            bf6_full(v1, cle, sle, 11);   // rd1 tail drains underneath; next: ren0 (VALU)
            // GrayA: deferred into next odd layer
        } else {
            // layer 7: finish stream1 B-phase; final Gray folds into epilogue scatter
            bf6_full(v1, cl, sl, 5);
        }
    }

    // ---- epilogue (B layout, Gray(7) folded): q[g(j)] = psi[j]^2,
    //      j = 64r + t, g(j) = 64*gray6(r) + (gray6(t) ^ 32*(r&1)) ----
#pragma unroll
    for (int i = 0; i < 32; ++i) {
        const int g0 = 64 * gray6(2 * i);
        const int g1 = 64 * (gray6(2 * i) ^ 1);
        lds[g0 + gtl]        = v0[i].x * v0[i].x;     // bank = gtl&31: 2-way, free
        lds[g1 + (gtl ^ 32)] = v0[i].y * v0[i].y;
        lds[SBF + g0 + gtl]        = v1[i].x * v1[i].x;
        lds[SBF + g1 + (gtl ^ 32)] = v1[i].y * v1[i].y;
    }

    float acc0[NCLASS], acc1[NCLASS];
#pragma unroll
    for (int c = 0; c < NCLASS; ++c) { acc0[c] = 0.f; acc1[c] = 0.f; }

#pragma unroll 1
    for (int k = 0; k < 16; ++k) {
        const v4f qa = *(const v4f*)(lds + 4 * t + 256 * k);         // b128, floor-free
        const v4f qb = *(const v4f*)(lds + SBF + 4 * t + 256 * k);
        const float* wp = W + 4 * t + 256 * k;
#pragma unroll
        for (int c = 0; c < NCLASS; ++c) {
            const v4f w4 = *(const v4f*)(wp + c * DIM);              // shared by both streams
            acc0[c] += qa.x * w4.x + qa.y * w4.y + qa.z * w4.z + qa.w * w4.w;
            acc1[c] += qb.x * w4.x + qb.y * w4.y + qb.z * w4.z + qb.w * w4.w;
        }
    }

#pragma unroll
    for (int c = 0; c < NCLASS; ++c) {
        float a0 = acc0[c], a1 = acc1[c];
#pragma unroll
        for (int o = 1; o < 64; o <<= 1) {
            a0 += __shfl_xor(a0, o, 64);
            a1 += __shfl_xor(a1, o, 64);
        }
        if (t == 0) {
            out[b0 * NCLASS + c] = fmaf(a0, invn0, bias[c]);
            if (has1) out[b1 * NCLASS + c] = fmaf(a1, invn1, bias[c]);
        }
    }
}

extern "C" void kernel_launch(void* const* d_in, const int* in_sizes, int n_in,
                              void* d_out, int out_size, void* d_ws, size_t ws_size,
                              hipStream_t stream) {
    const float* x    = (const float*)d_in[0];
    const float* ang  = (const float*)d_in[1];
    const float* W    = (const float*)d_in[2];
    const float* bias = (const float*)d_in[3];
    float* out = (float*)d_out;
    const int batch = in_sizes[0] / FEAT;   // 2048
    const int blocks = (batch + 1) / 2;     // 1024: two states per wave
    qnn_kernel<<<blocks, 64, 0, stream>>>(x, ang, W, bias, out, batch);
}

// Round 4
// 108.239 us; speedup vs baseline: 1.2131x; 1.2131x over previous
//
#include <hip/hip_runtime.h>
#include <math.h>

#define LAYERS  8
#define FEAT    3072
#define NCLASS  10
#define DIM     4096
#define ST      68   // padded LDS row stride (floats); ST%4==0 -> b128-able, ST%32==4

typedef float v2f __attribute__((ext_vector_type(2)));
typedef float v4f __attribute__((ext_vector_type(4)));

// prefix-xor (inverse Gray) of 6-bit value; compile-time under unroll
__device__ __forceinline__ int px6c(int r) {
    int u = r ^ (r >> 1); u ^= u >> 2; u ^= u >> 4; return u & 63;
}
__device__ __forceinline__ int gray6(int r) { return (r ^ (r >> 1)) & 63; }

__device__ __forceinline__ float getc(const v2f v[32], int u) {
    return (u & 1) ? v[u >> 1].y : v[u >> 1].x;
}
__device__ __forceinline__ void setc(v2f v[32], int u, float x) {
    if (u & 1) v[u >> 1].y = x; else v[u >> 1].x = x;
}
__device__ __forceinline__ float bpermf(int addr, float x) {
    return __int_as_float(__builtin_amdgcn_ds_bpermute(addr, __float_as_int(x)));
}

// ---- SHEAR butterflies: Ry(th) = cos(th) * [[1,-t],[t,1]], t = tan(th).
//      The cos factors are wave-uniform scalars of a LINEAR circuit -> all 96
//      commute out; C = prod(cos) is folded into invn2 as C^2 (exact rescale).
//      2 FMA per pair instead of 4 ops: halves butterfly VALU (the binding pipe).
//      Packed math is NOT used: gfx950 fp32 peak 157.3TF == scalar rate (R3 lesson).

// plain 6 register-qubit shear butterflies; reg bit p uses tl[off-p]
__device__ __forceinline__ void butterflies6t(v2f v[32],
                                              const float* __restrict__ tl,
                                              int off) {
    {
        const float tt = tl[off];
#pragma unroll
        for (int i = 0; i < 32; ++i) {
            v2f a = v[i];
            v[i].x = fmaf(-tt, a.y, a.x);    // x' = x - t*y
            v[i].y = fmaf( tt, a.x, a.y);    // y' = y + t*x (old x)
        }
    }
#pragma unroll
    for (int p = 1; p < 6; ++p) {
        const float tt = tl[off - p];
#pragma unroll
        for (int i0 = 0; i0 < 32; ++i0) {
            if (i0 & (1 << (p - 1))) continue;
            const int i1 = i0 | (1 << (p - 1));
            v2f a = v[i0], e = v[i1];
            v[i0].x = fmaf(-tt, e.x, a.x);   // a' = a - t*e
            v[i0].y = fmaf(-tt, e.y, a.y);
            v[i1].x = fmaf( tt, a.x, e.x);   // e' = e + t*a (old a)
            v[i1].y = fmaf( tt, a.y, e.y);
        }
    }
}

// A-phase CONJUGATED by the deferred GrayA (verified structure), shear form.
__device__ __forceinline__ void butterflies6_renamed_t(v2f v[32],
                                                       const float* __restrict__ tl,
                                                       float psgn) {
    {   // b=0: even k rotate (+t), odd k inverse (-t)
        const float tt = tl[11];
#pragma unroll
        for (int k = 0; k < 32; ++k) {
            v2f a = v[k];
            const float te = (k & 1) ? -tt : tt;
            v[k].x = fmaf(-te, a.y, a.x);
            v[k].y = fmaf( te, a.x, a.y);
        }
    }
#pragma unroll
    for (int b = 1; b < 5; ++b) {
        const float tt = tl[11 - b];
#pragma unroll
        for (int m = 0; m < 32; ++m) {
            if (m & (1 << (b - 1))) continue;
            const int part = m ^ ((1 << b) - 1);
            const float tg = (m & (1 << b)) ? -tt : tt;
            v2f A = v[m], E = v[part];
            v[m].x    = fmaf(-tg, E.y, A.x);   // A - tg*swap(E)
            v[m].y    = fmaf(-tg, E.x, A.y);
            v[part].x = fmaf( tg, A.y, E.x);   // E + tg*swap(A) (old A)
            v[part].y = fmaf( tg, A.x, E.y);
        }
    }
    {   // b=5: pairs (m, m^31), sign by lane parity (psgn)
        const float tt = psgn * tl[6];
#pragma unroll
        for (int m = 0; m < 16; ++m) {
            const int part = m ^ 31;
            v2f A = v[m], E = v[part];
            v[m].x    = fmaf(-tt, E.y, A.x);
            v[m].y    = fmaf(-tt, E.x, A.y);
            v[part].x = fmaf( tt, A.y, E.x);
            v[part].y = fmaf( tt, A.x, E.y);
        }
    }
}

__global__ __launch_bounds__(64)
void qnn_kernel(const float* __restrict__ x,
                const float* __restrict__ ang,
                const float* __restrict__ W,
                const float* __restrict__ bias,
                float* __restrict__ out)
{
    __shared__ __attribute__((aligned(16))) float lds[ST * 64];  // 17408 B
    __shared__ float tnt[96];

    const int t = threadIdx.x;          // 0..63, single wave per block/state
    const int b = blockIdx.x;

    // ---- tangent table (96 angles) + product of all 96 cosines ----
    float cprod2;
    {
        float a0 = ang[t];
        float c0 = cosf(a0), s0 = sinf(a0);
        tnt[t] = s0 / c0;
        float pc = c0;
        if (t < 32) {
            float a1 = ang[64 + t];
            float c1 = cosf(a1), s1 = sinf(a1);
            tnt[64 + t] = s1 / c1;
            pc *= c1;
        }
#pragma unroll
        for (int o = 1; o < 64; o <<= 1) pc *= __shfl_xor(pc, o, 64);
        cprod2 = pc * pc;               // (prod cos)^2, uniform across wave
    }

    // ---- load psi0 directly in B layout: v[r] = psi[64r + t] (coalesced b32) ----
    v2f v[32];
    {
        const float* xb = x + (size_t)b * FEAT;
#pragma unroll
        for (int r = 0; r < 64; ++r) {
            if (r < FEAT / 64) setc(v, r, xb[64 * r + t]);
            else               setc(v, r, 0.f);
        }
    }

    // ---- ||x||^2 (normalization deferred: circuit is linear); fold C^2 in ----
    float invn2;
    {
        v2f s2 = {0.f, 0.f};
#pragma unroll
        for (int i = 0; i < 32; ++i) s2 += v[i] * v[i];
        float ss = s2.x + s2.y;
#pragma unroll
        for (int o = 1; o < 64; o <<= 1) ss += __shfl_xor(ss, o, 64);
        invn2 = cprod2 / ss;
    }

    // ---- anti-lock-step skew keyed on the HW wave slot (distinct per SIMD) ----
    {
        const int slot = __builtin_amdgcn_s_getreg(4 | (0 << 6) | (3 << 11)) & 7;
#pragma unroll 1
        for (int i = 0; i < slot; ++i) __builtin_amdgcn_s_sleep(12);   // 12*64 cyc
    }

    // ---- per-lane constants ----
    int px = t ^ (t >> 1); px ^= px >> 2; px ^= px >> 4; px &= 63;  // px6(t)
    const int A0 = 4 * px;                    // bpermute byte addrs (GrayB)
    const int A1 = 4 * (px ^ 63);
    const int u0 = t & 1;
    const float psgn = u0 ? -1.f : 1.f;       // parity sign for renamed b=5
    const int gtl = gray6(t);
    const int bp  = gtl + 32 * ST * u0;       // folded-GrayA store bases
    const int bm  = gtl - 32 * ST * u0;

    // ---- layer 0 (even, clean): B-phase, transpose B->A, A-phase ----
    {
        const float* tl = tnt;
        butterflies6t(v, tl, 5);                      // qubits 5..0 (reg = hi bits)
#pragma unroll
        for (int i = 0; i < 16; ++i) {                // b128 rows: quads (17t+i)%8, floor-free
            v4f q = {v[2 * i].x, v[2 * i].y, v[2 * i + 1].x, v[2 * i + 1].y};
            *(v4f*)(lds + ST * t + 4 * i) = q;
        }
#pragma unroll
        for (int u = 0; u < 64; ++u)                  // b32 cols: bank (t+4u)%32, 2-way free
            setc(v, u, lds[t + ST * u]);
        butterflies6t(v, tl, 11);                     // qubits 11..6 (reg = lo bits)
        // GrayA(0): deferred into layer 1
    }

#pragma unroll 1
    for (int p = 0; p < 4; ++p) {
        // ======== odd layer 2p+1: renamed A-phase, folded transpose, B-phase ========
        {
            const float* tl = tnt + (2 * p + 1) * 12;

            butterflies6_renamed_t(v, tl, psgn);

            // transpose A->B with GrayA folded into store addresses:
            // element (lane t, reg s) -> addr = ((gray6(s)&32)? bm : bp) + ST*gray6(s)
#pragma unroll
            for (int s = 0; s < 64; ++s) {
                const int g = gray6(s);                       // compile-time
                lds[((g & 32) ? bm : bp) + ST * g] = getc(v, s);  // 2-way free
            }
#pragma unroll
            for (int i = 0; i < 16; ++i) {                    // b128 rows, floor-free
                v4f q = *(const v4f*)(lds + ST * t + 4 * i);
                v[2 * i]     = (v2f){q.x, q.y};
                v[2 * i + 1] = (v2f){q.z, q.w};
            }

            butterflies6t(v, tl, 5);                          // qubits 5..0

            if (p < 3) {
                // GrayB (eager): new[r] = bperm(parity(src)?A1:A0, old[px6(r)])
                float n[64];
#pragma unroll
                for (int r = 0; r < 64; ++r) {
                    const int srcr = px6c(r);                 // compile-time
                    n[r] = bpermf((srcr & 1) ? A1 : A0, getc(v, srcr));
                }
#pragma unroll
                for (int r = 0; r < 64; ++r)
                    setc(v, r, n[r]);
            }
            // p == 3 (layer 7): final Gray folds into the epilogue scatter
        }

        if (p == 3) break;

        // ======== even layer 2p+2 (clean): B-phase, transpose B->A, A-phase ========
        {
            const float* tl = tnt + (2 * p + 2) * 12;

            butterflies6t(v, tl, 5);
#pragma unroll
            for (int i = 0; i < 16; ++i) {
                v4f q = {v[2 * i].x, v[2 * i].y, v[2 * i + 1].x, v[2 * i + 1].y};
                *(v4f*)(lds + ST * t + 4 * i) = q;
            }
#pragma unroll
            for (int u = 0; u < 64; ++u)
                setc(v, u, lds[t + ST * u]);
            butterflies6t(v, tl, 11);
            // GrayA: deferred into next odd layer
        }
    }

    // ---- epilogue (B layout, Gray(7) folded): q[g(j)] = psi[j]^2,
    //      j = 64r + t, g(j) = 64*gray6(r) + (gray6(t) ^ 32*(r&1)) ----
#pragma unroll
    for (int i = 0; i < 32; ++i) {
        const int g0 = 64 * gray6(2 * i);
        const int g1 = 64 * (gray6(2 * i) ^ 1);
        lds[g0 + gtl]        = v[i].x * v[i].x;   // bank = gtl&31: 2-way, free
        lds[g1 + (gtl ^ 32)] = v[i].y * v[i].y;
    }

    float acc[NCLASS];
#pragma unroll
    for (int c = 0; c < NCLASS; ++c) acc[c] = 0.f;

#pragma unroll 1
    for (int k = 0; k < 16; ++k) {
        const v4f q4 = *(const v4f*)(lds + 4 * t + 256 * k);   // b128, floor-free
        const float* wp = W + 4 * t + 256 * k;
#pragma unroll
        for (int c = 0; c < NCLASS; ++c) {
            const v4f w4 = *(const v4f*)(wp + c * DIM);         // dwordx4, L2-resident
            acc[c] += q4.x * w4.x + q4.y * w4.y + q4.z * w4.z + q4.w * w4.w;
        }
    }

#pragma unroll
    for (int c = 0; c < NCLASS; ++c) {
        float a = acc[c];
#pragma unroll
        for (int o = 1; o < 64; o <<= 1) a += __shfl_xor(a, o, 64);
        if (t == 0) out[b * NCLASS + c] = fmaf(a, invn2, bias[c]);
    }
}

extern "C" void kernel_launch(void* const* d_in, const int* in_sizes, int n_in,
                              void* d_out, int out_size, void* d_ws, size_t ws_size,
                              hipStream_t stream) {
    const float* x    = (const float*)d_in[0];
    const float* ang  = (const float*)d_in[1];
    const float* W    = (const float*)d_in[2];
    const float* bias = (const float*)d_in[3];
    float* out = (float*)d_out;
    const int batch = in_sizes[0] / FEAT;   // 2048
    qnn_kernel<<<batch, 64, 0, stream>>>(x, ang, W, bias, out);
}

// Round 5
// 107.485 us; speedup vs baseline: 1.2216x; 1.0070x over previous
//
#include <hip/hip_runtime.h>
#include <math.h>

#define LAYERS  8
#define FEAT    3072
#define NCLASS  10
#define DIM     4096
#define ST      68   // padded LDS row stride (floats); ST%4==0 -> b128-able, ST%32==4

typedef float v2f __attribute__((ext_vector_type(2)));
typedef float v4f __attribute__((ext_vector_type(4)));

// prefix-xor (inverse Gray) of 6-bit value; compile-time under unroll
__device__ __forceinline__ int px6c(int r) {
    int u = r ^ (r >> 1); u ^= u >> 2; u ^= u >> 4; return u & 63;
}
__device__ __forceinline__ int gray6(int r) { return (r ^ (r >> 1)) & 63; }

__device__ __forceinline__ float getc(const v2f v[32], int u) {
    return (u & 1) ? v[u >> 1].y : v[u >> 1].x;
}
__device__ __forceinline__ void setc(v2f v[32], int u, float x) {
    if (u & 1) v[u >> 1].y = x; else v[u >> 1].x = x;
}
__device__ __forceinline__ float bpermf(int addr, float x) {
    return __int_as_float(__builtin_amdgcn_ds_bpermute(addr, __float_as_int(x)));
}

// ---- SHEAR butterflies: Ry(th) = cos(th) * [[1,-t],[t,1]], t = tan(th).
//      cos factors commute out of the linear circuit; C^2 folded into invn2.
//      (R4 verified; 2 FMA/pair. Packed fp32 is rate-neutral on gfx950 - R3.)

// plain 6 register-qubit shear butterflies; reg bit p uses tl[off-p]
__device__ __forceinline__ void butterflies6t(v2f v[32],
                                              const float* __restrict__ tl,
                                              int off) {
    {
        const float tt = tl[off];
#pragma unroll
        for (int i = 0; i < 32; ++i) {
            v2f a = v[i];
            v[i].x = fmaf(-tt, a.y, a.x);    // x' = x - t*y
            v[i].y = fmaf( tt, a.x, a.y);    // y' = y + t*x (old x)
        }
    }
#pragma unroll
    for (int p = 1; p < 6; ++p) {
        const float tt = tl[off - p];
#pragma unroll
        for (int i0 = 0; i0 < 32; ++i0) {
            if (i0 & (1 << (p - 1))) continue;
            const int i1 = i0 | (1 << (p - 1));
            v2f a = v[i0], e = v[i1];
            v[i0].x = fmaf(-tt, e.x, a.x);   // a' = a - t*e
            v[i0].y = fmaf(-tt, e.y, a.y);
            v[i1].x = fmaf( tt, a.x, e.x);   // e' = e + t*a (old a)
            v[i1].y = fmaf( tt, a.y, e.y);
        }
    }
}

// A-phase CONJUGATED by the deferred GrayA (verified structure), shear form.
__device__ __forceinline__ void butterflies6_renamed_t(v2f v[32],
                                                       const float* __restrict__ tl,
                                                       float psgn) {
    {   // b=0: even k rotate (+t), odd k inverse (-t)
        const float tt = tl[11];
#pragma unroll
        for (int k = 0; k < 32; ++k) {
            v2f a = v[k];
            const float te = (k & 1) ? -tt : tt;
            v[k].x = fmaf(-te, a.y, a.x);
            v[k].y = fmaf( te, a.x, a.y);
        }
    }
#pragma unroll
    for (int b = 1; b < 5; ++b) {
        const float tt = tl[11 - b];
#pragma unroll
        for (int m = 0; m < 32; ++m) {
            if (m & (1 << (b - 1))) continue;
            const int part = m ^ ((1 << b) - 1);
            const float tg = (m & (1 << b)) ? -tt : tt;
            v2f A = v[m], E = v[part];
            v[m].x    = fmaf(-tg, E.y, A.x);   // A - tg*swap(E)
            v[m].y    = fmaf(-tg, E.x, A.y);
            v[part].x = fmaf( tg, A.y, E.x);   // E + tg*swap(A) (old A)
            v[part].y = fmaf( tg, A.x, E.y);
        }
    }
    {   // b=5: pairs (m, m^31), sign by lane parity (psgn)
        const float tt = psgn * tl[6];
#pragma unroll
        for (int m = 0; m < 16; ++m) {
            const int part = m ^ 31;
            v2f A = v[m], E = v[part];
            v[m].x    = fmaf(-tt, E.y, A.x);
            v[m].y    = fmaf(-tt, E.x, A.y);
            v[part].x = fmaf( tt, A.y, E.x);
            v[part].y = fmaf( tt, A.x, E.y);
        }
    }
}

__global__ __launch_bounds__(64)
void qnn_kernel(const float* __restrict__ x,
                const float* __restrict__ ang,
                const float* __restrict__ W,
                const float* __restrict__ bias,
                float* __restrict__ out)
{
    __shared__ __attribute__((aligned(16))) float lds[ST * 64];  // 17408 B
    __shared__ float tnt[96];

    const int t = threadIdx.x;          // 0..63, single wave per block/state
    const int b = blockIdx.x;

    // ---- tangent table (96 angles) + product of all 96 cosines ----
    float cprod2;
    {
        float a0 = ang[t];
        float c0 = cosf(a0), s0 = sinf(a0);
        tnt[t] = s0 / c0;
        float pc = c0;
        if (t < 32) {
            float a1 = ang[64 + t];
            float c1 = cosf(a1), s1 = sinf(a1);
            tnt[64 + t] = s1 / c1;
            pc *= c1;
        }
#pragma unroll
        for (int o = 1; o < 64; o <<= 1) pc *= __shfl_xor(pc, o, 64);
        cprod2 = pc * pc;               // (prod cos)^2, uniform across wave
    }

    // ---- load psi0 directly in B layout: v[r] = psi[64r + t] (coalesced b32) ----
    v2f v[32];
    {
        const float* xb = x + (size_t)b * FEAT;
#pragma unroll
        for (int r = 0; r < 64; ++r) {
            if (r < FEAT / 64) setc(v, r, xb[64 * r + t]);
            else               setc(v, r, 0.f);
        }
    }

    // ---- ||x||^2 (normalization deferred: circuit is linear); fold C^2 in ----
    float invn2;
    {
        v2f s2 = {0.f, 0.f};
#pragma unroll
        for (int i = 0; i < 32; ++i) s2 += v[i] * v[i];
        float ss = s2.x + s2.y;
#pragma unroll
        for (int o = 1; o < 64; o <<= 1) ss += __shfl_xor(ss, o, 64);
        invn2 = cprod2 / ss;
    }

    // ---- anti-lock-step skew keyed on the HW wave slot (distinct per SIMD) ----
    {
        const int slot = __builtin_amdgcn_s_getreg(4 | (0 << 6) | (3 << 11)) & 7;
#pragma unroll 1
        for (int i = 0; i < slot; ++i) __builtin_amdgcn_s_sleep(12);   // 12*64 cyc
    }

    // ---- per-lane constants ----
    int px = t ^ (t >> 1); px ^= px >> 2; px ^= px >> 4; px &= 63;  // px6(t)
    const int A0 = 4 * px;                    // bpermute byte addrs (GrayB)
    const int A1 = 4 * (px ^ 63);
    const int u0 = t & 1;
    const float psgn = u0 ? -1.f : 1.f;       // parity sign for renamed b=5
    const int gtl = gray6(t);
    const int bp  = gtl + 32 * ST * u0;       // folded-GrayA store bases
    const int bm  = gtl - 32 * ST * u0;

    // ---- DS helpers. Addressing hygiene: per-4-row opaque bases keep all
    //      offsets < 1020B so SILoadStoreOptimizer merges b32 pairs into
    //      ds_read2_b32 / ds_write2_b32 (rows differ by ST=68 dwords <= 255).
    auto stRows = [&]() {                     // b128 row stores (B->A transpose)
#pragma unroll
        for (int i = 0; i < 16; ++i) {
            v4f q = {v[2 * i].x, v[2 * i].y, v[2 * i + 1].x, v[2 * i + 1].y};
            *(v4f*)(lds + ST * t + 4 * i) = q;
        }
    };
    auto rdCols = [&]() {                     // col reads -> ds_read2_b32 pairs
#pragma unroll
        for (int k = 0; k < 16; ++k) {
            int idx = t + ST * 4 * k;
            asm("" : "+v"(idx));              // opaque base per 4-row group
            float a0 = lds[idx];
            float a1 = lds[idx + ST];
            float a2 = lds[idx + 2 * ST];
            float a3 = lds[idx + 3 * ST];
            v[2 * k]     = (v2f){a0, a1};
            v[2 * k + 1] = (v2f){a2, a3};
        }
    };
    auto foldedStore = [&]() {                // A->B transpose, GrayA folded;
                                              // gray pairs -> ds_write2_b32
#pragma unroll
        for (int q = 0; q < 16; ++q) {
            const int s0  = 4 * q;
            const int g0  = gray6(s0);        // quad rows {g0,g0^1,g0^3,g0^2}
            const int blk = g0 & ~3;          // share bit5 -> same bp/bm base
            int idx = ((g0 & 32) ? bm : bp) + ST * blk;
            asm("" : "+v"(idx));
            lds[idx + ST * (gray6(s0)     - blk)] = getc(v, s0);
            lds[idx + ST * (gray6(s0 + 1) - blk)] = getc(v, s0 + 1);
            lds[idx + ST * (gray6(s0 + 2) - blk)] = getc(v, s0 + 2);
            lds[idx + ST * (gray6(s0 + 3) - blk)] = getc(v, s0 + 3);
        }
    };
    auto rowRead = [&]() {                    // b128 row reads
#pragma unroll
        for (int i = 0; i < 16; ++i) {
            v4f q = *(const v4f*)(lds + ST * t + 4 * i);
            v[2 * i]     = (v2f){q.x, q.y};
            v[2 * i + 1] = (v2f){q.z, q.w};
        }
    };

    // ---- layer 0 (even, clean): B-phase, transpose B->A, A-phase ----
    {
        float tb[12];
#pragma unroll
        for (int q = 0; q < 12; ++q) tb[q] = tnt[q];
        butterflies6t(v, tb, 5);                      // qubits 5..0 (reg = hi bits)
        stRows();
        rdCols();
        butterflies6t(v, tb, 11);                     // qubits 11..6 (reg = lo bits)
        // GrayA(0): deferred into layer 1
    }

#pragma unroll 1
    for (int p = 0; p < 4; ++p) {
        // ======== odd layer 2p+1: renamed A-phase, folded transpose, B-phase ========
        {
            float tb[12];
#pragma unroll
            for (int q = 0; q < 12; ++q) tb[q] = tnt[(2 * p + 1) * 12 + q];

            butterflies6_renamed_t(v, tb, psgn);
            foldedStore();
            rowRead();
            butterflies6t(v, tb, 5);                  // qubits 5..0

            if (p < 3) {
                // GrayB (eager): new[r] = bperm(parity(src)?A1:A0, old[px6(r)])
                float n[64];
#pragma unroll
                for (int r = 0; r < 64; ++r) {
                    const int srcr = px6c(r);         // compile-time
                    n[r] = bpermf((srcr & 1) ? A1 : A0, getc(v, srcr));
                }
#pragma unroll
                for (int r = 0; r < 64; ++r)
                    setc(v, r, n[r]);
            }
            // p == 3 (layer 7): final Gray folds into the epilogue scatter
        }

        if (p == 3) break;

        // ======== even layer 2p+2 (clean): B-phase, transpose B->A, A-phase ========
        {
            float tb[12];
#pragma unroll
            for (int q = 0; q < 12; ++q) tb[q] = tnt[(2 * p + 2) * 12 + q];

            butterflies6t(v, tb, 5);
            stRows();
            rdCols();
            butterflies6t(v, tb, 11);
            // GrayA: deferred into next odd layer
        }
    }

    // ---- epilogue (B layout, Gray(7) folded): q[g(j)] = psi[j]^2,
    //      j = 64r + t, g(j) = 64*gray6(r) + (gray6(t) ^ 32*(r&1)).
    //      Pairs (i,i+1) hit rows {G, G^3} of one 4-row block -> ds_write2_b32.
#pragma unroll
    for (int i2 = 0; i2 < 16; ++i2) {
        const int Ga = gray6(4 * i2);
        const int Gb = Ga ^ 3;                 // = gray6(4*i2 + 2)
        const int B  = Ga & ~3;
        int idxx = 64 * B + gtl;
        int idxy = 64 * B + (gtl ^ 32);
        asm("" : "+v"(idxx));
        asm("" : "+v"(idxy));
        const v2f va = v[2 * i2], vb = v[2 * i2 + 1];
        lds[idxx + 64 * (Ga - B)]       = va.x * va.x;   // bank = gtl&31: 2-way
        lds[idxx + 64 * (Gb - B)]       = vb.x * vb.x;
        lds[idxy + 64 * ((Ga ^ 1) - B)] = va.y * va.y;
        lds[idxy + 64 * ((Gb ^ 1) - B)] = vb.y * vb.y;
    }

    float acc[NCLASS];
#pragma unroll
    for (int c = 0; c < NCLASS; ++c) acc[c] = 0.f;

#pragma unroll 1
    for (int k = 0; k < 16; ++k) {
        const v4f q4 = *(const v4f*)(lds + 4 * t + 256 * k);   // b128, floor-free
        const float* wp = W + 4 * t + 256 * k;
#pragma unroll
        for (int c = 0; c < NCLASS; ++c) {
            const v4f w4 = *(const v4f*)(wp + c * DIM);         // dwordx4, L2-resident
            acc[c] += q4.x * w4.x + q4.y * w4.y + q4.z * w4.z + q4.w * w4.w;
        }
    }

#pragma unroll
    for (int c = 0; c < NCLASS; ++c) {
        float a = acc[c];
#pragma unroll
        for (int o = 1; o < 64; o <<= 1) a += __shfl_xor(a, o, 64);
        if (t == 0) out[b * NCLASS + c] = fmaf(a, invn2, bias[c]);
    }
}

extern "C" void kernel_launch(void* const* d_in, const int* in_sizes, int n_in,
                              void* d_out, int out_size, void* d_ws, size_t ws_size,
                              hipStream_t stream) {
    const float* x    = (const float*)d_in[0];
    const float* ang  = (const float*)d_in[1];
    const float* W    = (const float*)d_in[2];
    const float* bias = (const float*)d_in[3];
    float* out = (float*)d_out;
    const int batch = in_sizes[0] / FEAT;   // 2048
    qnn_kernel<<<batch, 64, 0, stream>>>(x, ang, W, bias, out);
}

// Round 6
// 106.305 us; speedup vs baseline: 1.2351x; 1.0111x over previous
//
#include <hip/hip_runtime.h>
#include <math.h>

#define LAYERS  8
#define FEAT    3072
#define NCLASS  10
#define DIM     4096
#define ST      68   // padded LDS row stride (floats); ST%4==0 -> b128-able, ST%32==4

typedef float v2f __attribute__((ext_vector_type(2)));
typedef float v4f __attribute__((ext_vector_type(4)));

// prefix-xor (inverse Gray) of 6-bit value; compile-time under unroll
__device__ __forceinline__ int px6c(int r) {
    int u = r ^ (r >> 1); u ^= u >> 2; u ^= u >> 4; return u & 63;
}
__device__ __forceinline__ int gray6(int r) { return (r ^ (r >> 1)) & 63; }

__device__ __forceinline__ float getc(const v2f v[32], int u) {
    return (u & 1) ? v[u >> 1].y : v[u >> 1].x;
}
__device__ __forceinline__ void setc(v2f v[32], int u, float x) {
    if (u & 1) v[u >> 1].y = x; else v[u >> 1].x = x;
}
__device__ __forceinline__ float bpermf(int addr, float x) {
    return __int_as_float(__builtin_amdgcn_ds_bpermute(addr, __float_as_int(x)));
}

// ---- SHEAR butterflies (R4, verified): Ry(th) = cos(th)*[[1,-t],[t,1]].
//      cos factors commute out; C^2 folded into invn2. 2 FMA per pair.
//      R6: stages on distinct qubits COMMUTE -> reordered so quad-local
//      stages (element bits 0,1) fuse with the b128 store / read of that
//      quad, pipelining the LDS transpose against butterfly FMAs.

// plain global stage on element-bit B (B>=2): reg pairs (i, i|(1<<(B-1)))
__device__ __forceinline__ void stageP(v2f v[32], int B, float tt) {
#pragma unroll
    for (int i0 = 0; i0 < 32; ++i0) {
        if (i0 & (1 << (B - 1))) continue;
        const int i1 = i0 | (1 << (B - 1));
        v2f a = v[i0], e = v[i1];
        v[i0].x = fmaf(-tt, e.x, a.x);
        v[i0].y = fmaf(-tt, e.y, a.y);
        v[i1].x = fmaf( tt, a.x, e.x);
        v[i1].y = fmaf( tt, a.y, e.y);
    }
}

// renamed global stage b (2..4): pairs (m, m^((1<<b)-1)), swapped partner
__device__ __forceinline__ void stageRb(v2f v[32], int b, float tt) {
#pragma unroll
    for (int m = 0; m < 32; ++m) {
        if (m & (1 << (b - 1))) continue;
        const int part = m ^ ((1 << b) - 1);
        const float tg = (m & (1 << b)) ? -tt : tt;
        v2f A = v[m], E = v[part];
        v[m].x    = fmaf(-tg, E.y, A.x);
        v[m].y    = fmaf(-tg, E.x, A.y);
        v[part].x = fmaf( tg, A.y, E.x);
        v[part].y = fmaf( tg, A.x, E.y);
    }
}
// renamed b=5: pairs (m, m^31), tt = psgn*tl[6]
__device__ __forceinline__ void stageR5(v2f v[32], float tt) {
#pragma unroll
    for (int m = 0; m < 16; ++m) {
        const int part = m ^ 31;
        v2f A = v[m], E = v[part];
        v[m].x    = fmaf(-tt, E.y, A.x);
        v[m].y    = fmaf(-tt, E.x, A.y);
        v[part].x = fmaf( tt, A.y, E.x);
        v[part].y = fmaf( tt, A.x, E.y);
    }
}

__global__ __launch_bounds__(64)
void qnn_kernel(const float* __restrict__ x,
                const float* __restrict__ ang,
                const float* __restrict__ W,
                const float* __restrict__ bias,
                float* __restrict__ out)
{
    __shared__ __attribute__((aligned(16))) float lds[ST * 64];  // 17408 B
    __shared__ float tnt[96];

    const int t = threadIdx.x;          // 0..63, single wave per block/state
    const int b = blockIdx.x;

    // ---- tangent table (96 angles) + product of all 96 cosines ----
    float cprod2;
    {
        float a0 = ang[t];
        float c0 = cosf(a0), s0 = sinf(a0);
        tnt[t] = s0 / c0;
        float pc = c0;
        if (t < 32) {
            float a1 = ang[64 + t];
            float c1 = cosf(a1), s1 = sinf(a1);
            tnt[64 + t] = s1 / c1;
            pc *= c1;
        }
#pragma unroll
        for (int o = 1; o < 64; o <<= 1) pc *= __shfl_xor(pc, o, 64);
        cprod2 = pc * pc;               // (prod cos)^2, uniform across wave
    }

    // ---- load psi0 directly in B layout: v[r] = psi[64r + t] (coalesced b32) ----
    v2f v[32];
    {
        const float* xb = x + (size_t)b * FEAT;
#pragma unroll
        for (int r = 0; r < 64; ++r) {
            if (r < FEAT / 64) setc(v, r, xb[64 * r + t]);
            else               setc(v, r, 0.f);
        }
    }

    // ---- ||x||^2 (normalization deferred: circuit is linear); fold C^2 in ----
    float invn2;
    {
        v2f s2 = {0.f, 0.f};
#pragma unroll
        for (int i = 0; i < 32; ++i) s2 += v[i] * v[i];
        float ss = s2.x + s2.y;
#pragma unroll
        for (int o = 1; o < 64; o <<= 1) ss += __shfl_xor(ss, o, 64);
        invn2 = cprod2 / ss;
    }

    // ---- anti-lock-step skew keyed on the HW wave slot (distinct per SIMD) ----
    {
        const int slot = __builtin_amdgcn_s_getreg(4 | (0 << 6) | (3 << 11)) & 7;
#pragma unroll 1
        for (int i = 0; i < slot; ++i) __builtin_amdgcn_s_sleep(12);   // 12*64 cyc
    }

    // ---- per-lane constants ----
    int px = t ^ (t >> 1); px ^= px >> 2; px ^= px >> 4; px &= 63;  // px6(t)
    const int A0 = 4 * px;                    // bpermute byte addrs (GrayB)
    const int A1 = 4 * (px ^ 63);
    const int u0 = t & 1;
    const float psgn = u0 ? -1.f : 1.f;       // parity sign for renamed b=5
    const int gtl = gray6(t);
    const int bp  = gtl + 32 * ST * u0;       // folded-GrayA store bases
    const int bm  = gtl - 32 * ST * u0;

    // ---- fused quad helpers (quad q = elements 4q..4q+3 = v[2q],v[2q+1]) ----

    // even/B-tail: bit0(t0) then bit1(t1) on quad, store b128 row chunk
    auto quadStoreB = [&](int q, float t1, float t0) {
        v2f a = v[2 * q], e = v[2 * q + 1];
        float b0 = fmaf(-t0, a.y, a.x), b1 = fmaf(t0, a.x, a.y);
        float b2 = fmaf(-t0, e.y, e.x), b3 = fmaf(t0, e.x, e.y);
        v4f qv = { fmaf(-t1, b2, b0), fmaf(-t1, b3, b1),
                   fmaf( t1, b0, b2), fmaf( t1, b1, b3) };
        *(v4f*)(lds + ST * t + 4 * q) = qv;
    };
    // A-head: 4 col reads -> bit0(t0) then bit1(t1)
    auto quadReadA = [&](int k, float t0, float t1) {
        const float a0 = lds[t + ST * (4 * k)];
        const float a1 = lds[t + ST * (4 * k + 1)];
        const float a2 = lds[t + ST * (4 * k + 2)];
        const float a3 = lds[t + ST * (4 * k + 3)];
        float b0 = fmaf(-t0, a1, a0), b1 = fmaf(t0, a0, a1);
        float b2 = fmaf(-t0, a3, a2), b3 = fmaf(t0, a2, a3);
        v[2 * k]     = (v2f){ fmaf(-t1, b2, b0), fmaf(-t1, b3, b1) };
        v[2 * k + 1] = (v2f){ fmaf( t1, b0, b2), fmaf( t1, b1, b3) };
    };
    // renamed tail: b=1(t10) then b=0(t11) on quad, folded-GrayA scatter
    auto quadStoreR = [&](int q, float t10, float t11) {
        v2f A = v[2 * q], E = v[2 * q + 1];
        const float tg = (q & 1) ? -t10 : t10;
        float nAx = fmaf(-tg, E.y, A.x), nAy = fmaf(-tg, E.x, A.y);
        float nEx = fmaf( tg, A.y, E.x), nEy = fmaf( tg, A.x, E.y);
        float r0 = fmaf(-t11, nAy, nAx);   // elem 4q   (even reg: te=+t11)
        float r1 = fmaf( t11, nAx, nAy);
        float r2 = fmaf( t11, nEy, nEx);   // elem 4q+2 (odd reg: te=-t11)
        float r3 = fmaf(-t11, nEx, nEy);
        const int g0 = gray6(4 * q);                 // compile-time
        const int base = ((g0 & 32) ? bm : bp);
        lds[base + ST * g0]       = r0;              // rows g0, g0^1, g0^3, g0^2
        lds[base + ST * (g0 ^ 1)] = r1;              // 2-way bank, free
        lds[base + ST * (g0 ^ 3)] = r2;
        lds[base + ST * (g0 ^ 2)] = r3;
    };
    // B-head: b128 row read -> bit0(t0) then bit1(t1)
    auto quadReadB = [&](int i, float t0, float t1) {
        v4f q4 = *(const v4f*)(lds + ST * t + 4 * i);
        float b0 = fmaf(-t0, q4.y, q4.x), b1 = fmaf(t0, q4.x, q4.y);
        float b2 = fmaf(-t0, q4.w, q4.z), b3 = fmaf(t0, q4.z, q4.w);
        v[2 * i]     = (v2f){ fmaf(-t1, b2, b0), fmaf(-t1, b3, b1) };
        v[2 * i + 1] = (v2f){ fmaf( t1, b0, b2), fmaf( t1, b1, b3) };
    };

    // ---- layer 0 (even, clean): B-phase, transpose B->A, A-phase ----
    {
        float tb[12];
#pragma unroll
        for (int q = 0; q < 12; ++q) tb[q] = tnt[q];
        // B-phase global bits 5..2 (tl[0..3]), then quad-fused bits 1,0 + store
        stageP(v, 5, tb[0]); stageP(v, 4, tb[1]);
        stageP(v, 3, tb[2]); stageP(v, 2, tb[3]);
#pragma unroll
        for (int q = 0; q < 16; ++q) quadStoreB(q, tb[4], tb[5]);
        // A-phase: quad-fused reads + bits 0,1 (tl[11],tl[10]), then global 2..5
#pragma unroll
        for (int k = 0; k < 16; ++k) quadReadA(k, tb[11], tb[10]);
        stageP(v, 2, tb[9]); stageP(v, 3, tb[8]);
        stageP(v, 4, tb[7]); stageP(v, 5, tb[6]);
        // GrayA(0): deferred into layer 1
    }

#pragma unroll 1
    for (int p = 0; p < 4; ++p) {
        // ======== odd layer 2p+1: renamed A-phase, folded transpose, B-phase ========
        {
            float tb[12];
#pragma unroll
            for (int q = 0; q < 12; ++q) tb[q] = tnt[(2 * p + 1) * 12 + q];

            // renamed global b=5,4,3,2 then quad-fused b=1,0 + GrayA scatter
            stageR5(v, psgn * tb[6]);
            stageRb(v, 4, tb[7]); stageRb(v, 3, tb[8]); stageRb(v, 2, tb[9]);
#pragma unroll
            for (int q = 0; q < 16; ++q) quadStoreR(q, tb[10], tb[11]);
            // B-phase: quad-fused row reads + bits 0,1 (tl[5],tl[4]), global 2..5
#pragma unroll
            for (int i = 0; i < 16; ++i) quadReadB(i, tb[5], tb[4]);
            stageP(v, 2, tb[3]); stageP(v, 3, tb[2]);
            stageP(v, 4, tb[1]); stageP(v, 5, tb[0]);

            if (p < 3) {
                // GrayB (eager): new[r] = bperm(parity(src)?A1:A0, old[px6(r)])
                float n[64];
#pragma unroll
                for (int r = 0; r < 64; ++r) {
                    const int srcr = px6c(r);         // compile-time
                    n[r] = bpermf((srcr & 1) ? A1 : A0, getc(v, srcr));
                }
#pragma unroll
                for (int r = 0; r < 64; ++r)
                    setc(v, r, n[r]);
            }
            // p == 3 (layer 7): final Gray folds into the epilogue scatter
        }

        if (p == 3) break;

        // ======== even layer 2p+2 (clean): B-phase, transpose B->A, A-phase ========
        {
            float tb[12];
#pragma unroll
            for (int q = 0; q < 12; ++q) tb[q] = tnt[(2 * p + 2) * 12 + q];

            stageP(v, 5, tb[0]); stageP(v, 4, tb[1]);
            stageP(v, 3, tb[2]); stageP(v, 2, tb[3]);
#pragma unroll
            for (int q = 0; q < 16; ++q) quadStoreB(q, tb[4], tb[5]);
#pragma unroll
            for (int k = 0; k < 16; ++k) quadReadA(k, tb[11], tb[10]);
            stageP(v, 2, tb[9]); stageP(v, 3, tb[8]);
            stageP(v, 4, tb[7]); stageP(v, 5, tb[6]);
            // GrayA: deferred into next odd layer
        }
    }

    // ---- epilogue (B layout, Gray(7) folded): q[g(j)] = psi[j]^2,
    //      j = 64r + t, g(j) = 64*gray6(r) + (gray6(t) ^ 32*(r&1)) ----
#pragma unroll
    for (int i = 0; i < 32; ++i) {
        const int g0 = 64 * gray6(2 * i);
        const int g1 = 64 * (gray6(2 * i) ^ 1);
        lds[g0 + gtl]        = v[i].x * v[i].x;   // bank = gtl&31: 2-way, free
        lds[g1 + (gtl ^ 32)] = v[i].y * v[i].y;
    }

    float acc[NCLASS];
#pragma unroll
    for (int c = 0; c < NCLASS; ++c) acc[c] = 0.f;

#pragma unroll 1
    for (int k = 0; k < 16; ++k) {
        const v4f q4 = *(const v4f*)(lds + 4 * t + 256 * k);   // b128, floor-free
        const float* wp = W + 4 * t + 256 * k;
#pragma unroll
        for (int c = 0; c < NCLASS; ++c) {
            const v4f w4 = *(const v4f*)(wp + c * DIM);         // dwordx4, L2-resident
            acc[c] += q4.x * w4.x + q4.y * w4.y + q4.z * w4.z + q4.w * w4.w;
        }
    }

#pragma unroll
    for (int c = 0; c < NCLASS; ++c) {
        float a = acc[c];
#pragma unroll
        for (int o = 1; o < 64; o <<= 1) a += __shfl_xor(a, o, 64);
        if (t == 0) out[b * NCLASS + c] = fmaf(a, invn2, bias[c]);
    }
}

extern "C" void kernel_launch(void* const* d_in, const int* in_sizes, int n_in,
                              void* d_out, int out_size, void* d_ws, size_t ws_size,
                              hipStream_t stream) {
    const float* x    = (const float*)d_in[0];
    const float* ang  = (const float*)d_in[1];
    const float* W    = (const float*)d_in[2];
    const float* bias = (const float*)d_in[3];
    float* out = (float*)d_out;
    const int batch = in_sizes[0] / FEAT;   // 2048
    qnn_kernel<<<batch, 64, 0, stream>>>(x, ang, W, bias, out);
}